// Round 1
// baseline (44.130 us; speedup 1.0000x reference)
//
#include <hip/hip_runtime.h>
#include <hip/hip_bf16.h>
#include <math.h>

typedef __bf16 bf16;
typedef __bf16 bf16x4 __attribute__((ext_vector_type(4)));
typedef __bf16 bf16x8 __attribute__((ext_vector_type(8)));
typedef float  f32x4  __attribute__((ext_vector_type(4)));

static constexpr int kTokens = 32768;   // B*S = 8*4096
static constexpr int kH  = 768;
static constexpr int kC  = 64;
static constexpr int kNW = 80;          // 64 e1 cols + 1 sc col + 15 zero pad (5 x 16)
static constexpr int kBK = 64;
static constexpr int kBM = 64;
static constexpr int kLDW = kBK + 8;    // +8 bf16 pad -> conflict-free b128 reads

// ---------- prep: build Wt[kNW][kH] bf16 = [W_e1^T | w_sc | 0...], and b_sc ----------
__global__ void prep_kernel(const float* __restrict__ W_ct,
                            const float* __restrict__ b_ct,
                            const float* __restrict__ W_cd,
                            const float* __restrict__ b_cd,
                            const float* __restrict__ W_e1,
                            bf16* __restrict__ Wt,
                            float* __restrict__ bsc) {
    int gidx = blockIdx.x * blockDim.x + threadIdx.x;
    const int total = kNW * kH;
    if (gidx < total) {
        int n = gidx / kH;
        int k = gidx - n * kH;
        float v = 0.f;
        if (n < kC) {
            v = W_e1[k * kC + n];                 // transpose of W_e1 (H,C)
        } else if (n == kC) {
            float s = 0.f;
            for (int c = 0; c < kC; ++c) s += W_ct[k * kC + c] * W_cd[c];
            v = s;                                // w_sc = W_ct @ W_cd
        }
        Wt[gidx] = (bf16)v;
    } else if (gidx == total) {
        float s = b_cd[0];
        for (int c = 0; c < kC; ++c) s += b_ct[c] * W_cd[c];
        bsc[0] = s;                               // b_sc = b_ct @ W_cd + b_cd
    }
}

// ---------- main: (32768 x 768) @ (768 x 80) bf16 MFMA + fused epilogue ----------
__global__ __launch_bounds__(256) void incong_main(
    const float* __restrict__ hs,      // [kTokens][kH] f32
    const bf16*  __restrict__ Wt,      // [kNW][kH] bf16
    const float* __restrict__ bsc_p,
    const float* __restrict__ b_e1,
    const float* __restrict__ W_e2,
    const float* __restrict__ b_e2,
    float* __restrict__ out)           // [3][kTokens]
{
    __shared__ bf16 lds_a[kBM][kLDW];
    __shared__ bf16 lds_w[kNW][kLDW];

    const int tid  = threadIdx.x;
    const int lane = tid & 63;
    const int wv   = tid >> 6;         // wave 0..3 -> 16-token band
    const int tok0 = blockIdx.x * kBM;
    const int r16  = lane & 15;
    const int kg   = lane >> 4;        // 0..3

    f32x4 acc[5];
    #pragma unroll
    for (int n = 0; n < 5; ++n) acc[n] = (f32x4){0.f, 0.f, 0.f, 0.f};

    for (int kk = 0; kk < kH; kk += kBK) {
        // stage A tile: kBM x kBK f32 -> bf16 (coalesced float4 loads)
        #pragma unroll
        for (int idx = tid; idx < kBM * kBK / 4; idx += 256) {
            int row = idx >> 4;
            int ko  = (idx & 15) * 4;
            const float4 v = *reinterpret_cast<const float4*>(
                &hs[(size_t)(tok0 + row) * kH + kk + ko]);
            bf16x4 p;
            p[0] = (bf16)v.x; p[1] = (bf16)v.y; p[2] = (bf16)v.z; p[3] = (bf16)v.w;
            *reinterpret_cast<bf16x4*>(&lds_a[row][ko]) = p;
        }
        // stage W chunk: kNW x kBK bf16 (L2-resident)
        #pragma unroll
        for (int c = tid; c < kNW * kBK / 8; c += 256) {
            int row = c >> 3;
            int ko  = (c & 7) * 8;
            *reinterpret_cast<bf16x8*>(&lds_w[row][ko]) =
                *reinterpret_cast<const bf16x8*>(&Wt[(size_t)row * kH + kk + ko]);
        }
        __syncthreads();
        #pragma unroll
        for (int ks = 0; ks < kBK; ks += 32) {
            bf16x8 af = *reinterpret_cast<const bf16x8*>(
                &lds_a[wv * 16 + r16][ks + kg * 8]);
            #pragma unroll
            for (int n = 0; n < 5; ++n) {
                bf16x8 bfr = *reinterpret_cast<const bf16x8*>(
                    &lds_w[n * 16 + r16][ks + kg * 8]);
                acc[n] = __builtin_amdgcn_mfma_f32_16x16x32_bf16(af, bfr, acc[n], 0, 0, 0);
            }
        }
        __syncthreads();
    }

    // Epilogue. D layout (m89-verified): col = lane&15, row = (lane>>4)*4 + reg.
    float part[4] = {0.f, 0.f, 0.f, 0.f};
    #pragma unroll
    for (int n = 0; n < 4; ++n) {
        int cidx = n * 16 + r16;
        float be = b_e1[cidx];
        float we = W_e2[cidx];
        #pragma unroll
        for (int r = 0; r < 4; ++r) {
            float e = acc[n][r] + be;
            part[r] += fmaxf(e, 0.f) * we;
        }
    }
    // reduce over the 16 lanes (cols) sharing this kg
    #pragma unroll
    for (int m = 1; m < 16; m <<= 1) {
        #pragma unroll
        for (int r = 0; r < 4; ++r) part[r] += __shfl_xor(part[r], m);
    }
    if (r16 == 0) {
        float bsc = bsc_p[0];
        float be2 = b_e2[0];
        #pragma unroll
        for (int r = 0; r < 4; ++r) {
            int tok = tok0 + wv * 16 + kg * 4 + r;
            float sc = acc[4][r] + bsc;          // col 64 = w_sc column
            out[tok]               = 1.f / (1.f + __expf(-sc));
            out[kTokens + tok]     = 1.f / (1.f + __expf(-(part[r] + be2)));
            out[2 * kTokens + tok] = 1.f / 4096.f;   // mean of softmax == 1/S
        }
    }
}

extern "C" void kernel_launch(void* const* d_in, const int* in_sizes, int n_in,
                              void* d_out, int out_size, void* d_ws, size_t ws_size,
                              hipStream_t stream) {
    const float* hs   = (const float*)d_in[0];
    // d_in[1] = attention_mask (all ones, unused by the reference math)
    const float* W_ct = (const float*)d_in[2];
    const float* b_ct = (const float*)d_in[3];
    const float* W_cd = (const float*)d_in[4];
    const float* b_cd = (const float*)d_in[5];
    const float* W_e1 = (const float*)d_in[6];
    const float* b_e1 = (const float*)d_in[7];
    const float* W_e2 = (const float*)d_in[8];
    const float* b_e2 = (const float*)d_in[9];
    // d_in[10..13] = W_q, b_q, W_k, b_k — unused (surprise is exactly 1/S)

    bf16*  Wt  = (bf16*)d_ws;
    float* bsc = (float*)((char*)d_ws + (size_t)kNW * kH * sizeof(bf16));

    const int prep_total = kNW * kH + 1;
    prep_kernel<<<(prep_total + 255) / 256, 256, 0, stream>>>(
        W_ct, b_ct, W_cd, b_cd, W_e1, Wt, bsc);

    incong_main<<<kTokens / kBM, 256, 0, stream>>>(
        hs, Wt, bsc, b_e1, W_e2, b_e2, (float*)d_out);
}